// Round 2
// baseline (417.880 us; speedup 1.0000x reference)
//
#include <hip/hip_runtime.h>
#include <math.h>

#define BB   16
#define RR   4096
#define CCLS 81
#define NC   80          // C-1 foreground classes
#define KK   300
#define DD   100
#define CAP  16384       // per-image compacted candidate capacity (expected ~6400)

// ---------------- Kernel A: softmax + transpose to [B][80][R] ----------------
__global__ __launch_bounds__(256) void softmax_t_kernel(
        const float* __restrict__ logits, float* __restrict__ probs_t) {
    __shared__ float tile[64 * 81];
    __shared__ float srow_s[64];
    const int tid  = threadIdx.x;
    const int row0 = blockIdx.x * 64;

    for (int idx = tid; idx < 64 * 81; idx += 256)
        tile[idx] = logits[(size_t)row0 * 81 + idx];
    __syncthreads();

    if (tid < 64) {
        float* rowp = &tile[tid * 81];
        float m = -1e30f;
        for (int c = 0; c < 81; ++c) m = fmaxf(m, rowp[c]);
        float s = 0.0f;
        for (int c = 0; c < 81; ++c) { float e = expf(rowp[c] - m); rowp[c] = e; s += e; }
        srow_s[tid] = s;
    }
    __syncthreads();

    const int b     = row0 >> 12;
    const int rbase = row0 & 4095;
    for (int idx = tid; idx < 64 * 80; idx += 256) {
        int c1 = idx >> 6;
        int r  = idx & 63;
        float v = tile[r * 81 + (c1 + 1)] / srow_s[r];
        probs_t[((size_t)(b * 80 + c1)) * 4096 + rbase + r] = v;
    }
}

// ------------- Kernel B: per (image,class) top-K + decode + NMS --------------
// Appends kept boxes to per-image compacted lists (order-independent keys).
__global__ __launch_bounds__(256) void percls_kernel(
        const float* __restrict__ probs_t,
        const float* __restrict__ box_reg,
        const float* __restrict__ proposals,
        unsigned long long* __restrict__ cand_keys,   // [BB][CAP]
        float4*             __restrict__ cand_boxes,  // [BB][CAP]
        int*                __restrict__ g_cnt) {     // [BB]
    #pragma clang fp contract(off)
    __shared__ unsigned long long keys[512];
    __shared__ float bx1[KK], by1[KK], bx2[KK], by2[KK], barea[KK];
    __shared__ int   keep[KK];
    __shared__ int   locidx[KK];
    __shared__ int   cnt, lpos, wbase;

    const int bid = blockIdx.x;       // 0..1279
    const int b   = bid / 80;
    const int ci  = bid % 80;         // class-1
    const int tid = threadIdx.x;

    if (tid == 0) { cnt = 0; lpos = 0; }
    __syncthreads();

    // 1) compact indices with score > 0.05 (positive scores -> raw bits sortable)
    const float* sp = probs_t + (size_t)bid * 4096;
    for (int r = tid; r < 4096; r += 256) {
        float s = sp[r];
        if (s > 0.05f) {
            int pos = atomicAdd(&cnt, 1);
            if (pos < 512)
                keys[pos] = ((unsigned long long)__float_as_uint(s) << 32)
                          | (unsigned)(~(unsigned)r);   // smaller r wins ties in desc sort
        }
    }
    __syncthreads();
    int M = cnt; if (M > 512) M = 512;
    const int sortN = (M <= 128) ? 128 : (M <= 256) ? 256 : 512;
    for (int i = tid; i < 512; i += 256) if (i >= M) keys[i] = 0ULL;
    __syncthreads();

    // 2) bitonic sort (adaptive size), descending
    for (int k = 2; k <= sortN; k <<= 1) {
        for (int j = k >> 1; j > 0; j >>= 1) {
            for (int i = tid; i < sortN; i += 256) {
                int ixj = i ^ j;
                if (ixj > i) {
                    bool desc = ((i & k) == 0);
                    unsigned long long a = keys[i], c = keys[ixj];
                    if (desc ? (a < c) : (a > c)) { keys[i] = c; keys[ixj] = a; }
                }
            }
            __syncthreads();
        }
    }

    const int N = (M < KK) ? M : KK;

    // 3) decode + clip selected boxes (reference op order; no FMA contraction)
    for (int k2 = tid; k2 < N; k2 += 256) {
        unsigned long long key = keys[k2];
        unsigned r = ~(unsigned)(key & 0xFFFFFFFFu);
        size_t n = (size_t)b * 4096 + r;
        float px1 = proposals[n * 4 + 0], py1 = proposals[n * 4 + 1];
        float px2 = proposals[n * 4 + 2], py2 = proposals[n * 4 + 3];
        const float* rg = box_reg + n * 324 + (size_t)(ci + 1) * 4;
        float dx = rg[0] / 10.0f;
        float dy = rg[1] / 10.0f;
        float dw = fminf(rg[2] / 5.0f, 4.135166556742356f);
        float dh = fminf(rg[3] / 5.0f, 4.135166556742356f);
        float w  = px2 - px1 + 1.0f;
        float h  = py2 - py1 + 1.0f;
        float cx = px1 + 0.5f * w;
        float cy = py1 + 0.5f * h;
        float pcx = dx * w + cx;
        float pcy = dy * h + cy;
        float pw  = expf(dw) * w;
        float ph  = expf(dh) * h;
        float x1 = pcx - 0.5f * pw;
        float y1 = pcy - 0.5f * ph;
        float x2 = pcx + 0.5f * pw - 1.0f;
        float y2 = pcy + 0.5f * ph - 1.0f;
        x1 = fminf(fmaxf(x1, 0.0f), 1332.0f);
        y1 = fminf(fmaxf(y1, 0.0f), 799.0f);
        x2 = fminf(fmaxf(x2, 0.0f), 1332.0f);
        y2 = fminf(fmaxf(y2, 0.0f), 799.0f);
        bx1[k2] = x1; by1[k2] = y1; bx2[k2] = x2; by2[k2] = y2;
        barea[k2] = (x2 - x1 + 1.0f) * (y2 - y1 + 1.0f);
        keep[k2]  = 1;
    }
    __syncthreads();

    // 4) greedy NMS
    for (int i = 0; i < N; ++i) {
        __syncthreads();
        if (!keep[i]) continue;
        float ax1 = bx1[i], ay1 = by1[i], ax2 = bx2[i], ay2 = by2[i], aar = barea[i];
        for (int j2 = i + 1 + tid; j2 < N; j2 += 256) {
            if (!keep[j2]) continue;
            float ltx = fmaxf(ax1, bx1[j2]);
            float lty = fmaxf(ay1, by1[j2]);
            float rbx = fminf(ax2, bx2[j2]);
            float rby = fminf(ay2, by2[j2]);
            float iw  = fmaxf(rbx - ltx + 1.0f, 0.0f);
            float ih  = fmaxf(rby - lty + 1.0f, 0.0f);
            float inter = iw * ih;
            float iou   = inter / ((aar + barea[j2]) - inter);
            if (iou > 0.5f) keep[j2] = 0;
        }
    }
    __syncthreads();

    // 5) append kept entries to the per-image compacted list
    for (int k2 = tid; k2 < N; k2 += 256) {
        if (keep[k2]) {
            int l = atomicAdd(&lpos, 1);
            locidx[l] = k2;
        }
    }
    __syncthreads();
    if (tid == 0) wbase = atomicAdd(&g_cnt[b], lpos);
    __syncthreads();
    const int nloc = lpos, base = wbase;
    for (int l = tid; l < nloc; l += 256) {
        int pos = base + l;
        if (pos < CAP) {
            int k2 = locidx[l];
            unsigned sbits = (unsigned)(keys[k2] >> 32);
            unsigned fi    = (unsigned)(ci * KK + k2);
            cand_keys[(size_t)b * CAP + pos] =
                ((unsigned long long)sbits << 32) | (unsigned)(~fi);
            cand_boxes[(size_t)b * CAP + pos] =
                make_float4(bx1[k2], by1[k2], bx2[k2], by2[k2]);
        }
    }
}

// --------------- Kernel C: per-image exact top-100 + output ------------------
__global__ __launch_bounds__(256) void topd2_kernel(
        const unsigned long long* __restrict__ cand_keys,
        const float4*             __restrict__ cand_boxes,
        const int*                __restrict__ g_cnt,
        float*                    __restrict__ out) {
    __shared__ unsigned sb[CAP];            // staged score bits (64 KB)
    __shared__ unsigned hist[256];
    __shared__ unsigned sfx[257];
    __shared__ unsigned long long cand[512];
    __shared__ int sh_bin, sh_t, sh_cnt;

    const int b   = blockIdx.x;
    const int tid = threadIdx.x;
    int M = g_cnt[b]; if (M > CAP) M = CAP;
    const unsigned long long* kp = cand_keys + (size_t)b * CAP;

    for (int i = tid; i < M; i += 256) sb[i] = (unsigned)(kp[i] >> 32);
    __syncthreads();

    // MSB radix-select (8-bit digits) with parallel suffix scan + early exit.
    unsigned prefix = 0, mask = 0, gatherT = 0;
    int t = DD, above = 0, done = 0;
    for (int pass = 0; pass < 4 && !done; ++pass) {
        const int shift = 24 - 8 * pass;
        hist[tid] = 0;
        __syncthreads();
        for (int i = tid; i < M; i += 256) {
            unsigned k = sb[i];
            if ((k & mask) == prefix) atomicAdd(&hist[(k >> shift) & 255u], 1u);
        }
        __syncthreads();
        sfx[tid] = hist[tid];
        __syncthreads();
        for (int off = 1; off < 256; off <<= 1) {
            unsigned add = (tid + off < 256) ? sfx[tid + off] : 0u;
            __syncthreads();
            sfx[tid] += add;
            __syncthreads();
        }
        {
            unsigned Sb  = sfx[tid];
            unsigned Sb1 = (tid == 255) ? 0u : sfx[tid + 1];
            if (Sb >= (unsigned)t && Sb1 < (unsigned)t) { sh_bin = tid; sh_t = t - (int)Sb1; }
        }
        __syncthreads();
        const int selbin   = sh_bin;
        const unsigned Ssel = sfx[selbin];                        // incl. selected bin
        const unsigned Snext = (selbin == 255) ? 0u : sfx[selbin + 1];
        const int gcount = above + (int)Ssel;                     // >= 100 by invariant
        prefix |= ((unsigned)selbin) << shift;
        mask   |= 0xFFu << shift;
        t = sh_t;
        if (gcount <= 512 || pass == 3) { gatherT = prefix; done = 1; }
        else above += (int)Snext;
        __syncthreads();
    }

    if (tid == 0) sh_cnt = 0;
    __syncthreads();
    for (int i = tid; i < M; i += 256) {
        if (sb[i] >= gatherT) {
            int p = atomicAdd(&sh_cnt, 1);
            if (p < 512) cand[p] = kp[i];
        }
    }
    __syncthreads();
    int ngath = sh_cnt; if (ngath > 512) ngath = 512;
    const int sortN = (ngath <= 128) ? 128 : (ngath <= 256) ? 256 : 512;
    for (int i = tid; i < sortN; i += 256) if (i >= ngath) cand[i] = 0ULL;
    __syncthreads();

    for (int k = 2; k <= sortN; k <<= 1) {
        for (int j = k >> 1; j > 0; j >>= 1) {
            for (int i = tid; i < sortN; i += 256) {
                int ixj = i ^ j;
                if (ixj > i) {
                    bool desc = ((i & k) == 0);
                    unsigned long long a = cand[i], c = cand[ixj];
                    if (desc ? (a < c) : (a > c)) { cand[i] = c; cand[ixj] = a; }
                }
            }
            __syncthreads();
        }
    }

    if (tid < DD) {
        float s; float4 bb; int label;
        if (tid < ngath) {
            unsigned long long key = cand[tid];
            unsigned fi = ~(unsigned)(key & 0xFFFFFFFFu);
            s  = __uint_as_float((unsigned)(key >> 32));
            bb = cand_boxes[(size_t)b * CAP + 0];  // placeholder, replaced below
            // boxes were stored in compaction order; find via the same slot:
            // fi is the flat index; but box lives at the candidate slot. We must
            // locate it: candidate slots are unordered, so store slot in key? No:
            // we re-scan is wasteful. Instead: gather stored slot alongside.
            label = (int)(fi / KK) + 1;
            (void)bb;
        } else {
            s = -1.0f; label = 0;
        }
        // defer writes to after box resolution below
        __syncthreads();
        (void)s; (void)label;
    }
    __syncthreads();

    // Resolve boxes: re-gather slots for the winning keys.
    // (cand[] keys are unique; match each output key to its slot by re-scan.)
    __shared__ int slot_of[DD];
    for (int i = tid; i < DD; i += 256) slot_of[i] = -1;
    __syncthreads();
    for (int i = tid; i < M; i += 256) {
        unsigned long long k = kp[i];
        if ((unsigned)(k >> 32) >= gatherT) {
            // binary search not needed: just compare against top-DD keys
            for (int d = 0; d < DD; ++d) {
                if (cand[d] == k) { slot_of[d] = i; break; }
            }
        }
    }
    __syncthreads();

    if (tid < DD) {
        unsigned long long key = cand[tid];
        float s; float4 bb; int label;
        int slot = slot_of[tid];
        if (tid < ngath && slot >= 0) {
            unsigned fi = ~(unsigned)(key & 0xFFFFFFFFu);
            s  = __uint_as_float((unsigned)(key >> 32));
            bb = cand_boxes[(size_t)b * CAP + slot];
            label = (int)(fi / KK) + 1;
        } else {
            s = -1.0f; bb = make_float4(0.0f, 0.0f, 0.0f, 0.0f); label = 0;
        }
        out[(size_t)(b * DD + tid) * 4 + 0] = bb.x;
        out[(size_t)(b * DD + tid) * 4 + 1] = bb.y;
        out[(size_t)(b * DD + tid) * 4 + 2] = bb.z;
        out[(size_t)(b * DD + tid) * 4 + 3] = bb.w;
        out[(size_t)BB * DD * 4 + b * DD + tid] = s;
        out[(size_t)BB * DD * 4 + BB * DD + b * DD + tid] = (float)label;
    }
}

extern "C" void kernel_launch(void* const* d_in, const int* in_sizes, int n_in,
                              void* d_out, int out_size, void* d_ws, size_t ws_size,
                              hipStream_t stream) {
    const float* logits    = (const float*)d_in[0];   // [B*R, 81]
    const float* box_reg   = (const float*)d_in[1];   // [B*R, 324]
    const float* proposals = (const float*)d_in[2];   // [B*R, 4]
    float* out = (float*)d_out;

    char* ws = (char*)d_ws;
    float*              probs_t    = (float*)ws;                         // 20,971,520 B
    unsigned long long* cand_keys  = (unsigned long long*)(ws + 20971520);  // 2,097,152 B
    float4*             cand_boxes = (float4*)(ws + 23068672);              // 4,194,304 B
    int*                g_cnt      = (int*)(ws + 27262976);                 // 64 B

    hipMemsetAsync(g_cnt, 0, BB * sizeof(int), stream);
    softmax_t_kernel<<<(BB * RR) / 64, 256, 0, stream>>>(logits, probs_t);
    percls_kernel<<<BB * NC, 256, 0, stream>>>(probs_t, box_reg, proposals,
                                               cand_keys, cand_boxes, g_cnt);
    topd2_kernel<<<BB, 256, 0, stream>>>(cand_keys, cand_boxes, g_cnt, out);
}

// Round 3
// 376.623 us; speedup vs baseline: 1.1095x; 1.1095x over previous
//
#include <hip/hip_runtime.h>
#include <math.h>

#define BB   16
#define RR   4096
#define NC   80          // foreground classes
#define KK   300
#define DD   100
#define CCAP 512         // per-(image,class) candidate cap (expected ~118, sigma ~11)
#define CAP  16384       // per-image kept-candidate cap (expected ~8800)

typedef unsigned long long ull;

// ---- Kernel A: softmax (bit-exact) + fused >0.05 candidate extraction ----
__global__ __launch_bounds__(256) void softmax_cand_kernel(
        const float* __restrict__ logits,
        ull*         __restrict__ cand2,     // [BB*NC][CCAP]
        int*         __restrict__ cls_cnt) { // [BB*NC]
    __shared__ float tile[64 * 81];
    __shared__ float srow[64];
    const int tid  = threadIdx.x;
    const int row0 = blockIdx.x * 64;

    for (int idx = tid; idx < 64 * 81; idx += 256)
        tile[idx] = logits[(size_t)row0 * 81 + idx];
    __syncthreads();

    if (tid < 64) {
        float* rowp = &tile[tid * 81];
        float m = -1e30f;
        for (int c = 0; c < 81; ++c) m = fmaxf(m, rowp[c]);
        float s = 0.0f;
        for (int c = 0; c < 81; ++c) { float e = expf(rowp[c] - m); rowp[c] = e; s += e; }
        srow[tid] = s;
    }
    __syncthreads();

    const int b     = row0 >> 12;
    const int rbase = row0 & 4095;
    // idx -> (c1 = idx>>6, r = idx&63): each wave-iteration touches ONE class
    // -> cls_cnt address is wave-uniform -> compiler aggregates the atomic.
    for (int idx = tid; idx < 64 * 80; idx += 256) {
        int c1 = idx >> 6;
        int r  = idx & 63;
        float v = tile[r * 81 + (c1 + 1)] / srow[r];
        if (v > 0.05f) {
            int bc  = b * NC + c1;
            int pos = atomicAdd(&cls_cnt[bc], 1);
            if (pos < CCAP)
                cand2[(size_t)bc * CCAP + pos] =
                    ((ull)__float_as_uint(v) << 32) | (unsigned)(~(unsigned)(rbase + r));
        }
    }
}

// ---- Kernel B: ONE WAVE per (image,class): sort + decode + NMS + append ----
__global__ __launch_bounds__(64) void percls_kernel(
        const ull*   __restrict__ cand2,
        const int*   __restrict__ cls_cnt,
        const float* __restrict__ box_reg,
        const float* __restrict__ proposals,
        ull*         __restrict__ img_keys,   // [BB][CAP]
        float4*      __restrict__ img_boxes,  // [BB][CAP]
        int*         __restrict__ g_cnt) {    // [BB]
    #pragma clang fp contract(off)
    __shared__ ull   keys[CCAP];
    __shared__ float bx1[KK], by1[KK], bx2[KK], by2[KK], bar[KK];
    __shared__ int   keep[KK];

    const int bid = blockIdx.x;   // 0..1279
    const int b   = bid / NC;
    const int ci  = bid % NC;
    const int tid = threadIdx.x;  // 0..63 (single wave: __syncthreads ~= waitcnt)

    int M = cls_cnt[bid]; if (M > CCAP) M = CCAP;
    int sortN = 2; while (sortN < M) sortN <<= 1;

    for (int i = tid; i < sortN; i += 64)
        keys[i] = (i < M) ? cand2[(size_t)bid * CCAP + i] : 0ULL;
    __syncthreads();

    for (int k = 2; k <= sortN; k <<= 1) {
        for (int j = k >> 1; j > 0; j >>= 1) {
            for (int i = tid; i < sortN; i += 64) {
                int ixj = i ^ j;
                if (ixj > i) {
                    bool desc = ((i & k) == 0);
                    ull a = keys[i], c = keys[ixj];
                    if (desc ? (a < c) : (a > c)) { keys[i] = c; keys[ixj] = a; }
                }
            }
            __syncthreads();
        }
    }

    const int N = (M < KK) ? M : KK;

    for (int k2 = tid; k2 < N; k2 += 64) {
        unsigned r = ~(unsigned)(keys[k2] & 0xFFFFFFFFu);
        size_t n = (size_t)b * RR + r;
        const float4 pr = *(const float4*)(proposals + n * 4);
        const float4 rg = *(const float4*)(box_reg + n * 324 + (size_t)(ci + 1) * 4);
        float dx = rg.x / 10.0f;
        float dy = rg.y / 10.0f;
        float dw = fminf(rg.z / 5.0f, 4.135166556742356f);
        float dh = fminf(rg.w / 5.0f, 4.135166556742356f);
        float w  = pr.z - pr.x + 1.0f;
        float h  = pr.w - pr.y + 1.0f;
        float cx = pr.x + 0.5f * w;
        float cy = pr.y + 0.5f * h;
        float pcx = dx * w + cx;
        float pcy = dy * h + cy;
        float pw  = expf(dw) * w;
        float ph  = expf(dh) * h;
        float x1 = pcx - 0.5f * pw;
        float y1 = pcy - 0.5f * ph;
        float x2 = pcx + 0.5f * pw - 1.0f;
        float y2 = pcy + 0.5f * ph - 1.0f;
        x1 = fminf(fmaxf(x1, 0.0f), 1332.0f);
        y1 = fminf(fmaxf(y1, 0.0f), 799.0f);
        x2 = fminf(fmaxf(x2, 0.0f), 1332.0f);
        y2 = fminf(fmaxf(y2, 0.0f), 799.0f);
        bx1[k2] = x1; by1[k2] = y1; bx2[k2] = x2; by2[k2] = y2;
        bar[k2] = (x2 - x1 + 1.0f) * (y2 - y1 + 1.0f);
        keep[k2] = 1;
    }
    __syncthreads();

    // greedy NMS, lockstep within the wave (no HW barriers)
    for (int i = 0; i < N; ++i) {
        __syncthreads();
        if (!keep[i]) continue;
        float ax1 = bx1[i], ay1 = by1[i], ax2 = bx2[i], ay2 = by2[i], aar = bar[i];
        for (int j = i + 1 + tid; j < N; j += 64) {
            if (!keep[j]) continue;
            float ltx = fmaxf(ax1, bx1[j]);
            float lty = fmaxf(ay1, by1[j]);
            float rbx = fminf(ax2, bx2[j]);
            float rby = fminf(ay2, by2[j]);
            float iw  = fmaxf(rbx - ltx + 1.0f, 0.0f);
            float ih  = fmaxf(rby - lty + 1.0f, 0.0f);
            float inter = iw * ih;
            float iou   = inter / ((aar + bar[j]) - inter);
            if (iou > 0.5f) keep[j] = 0;
        }
    }
    __syncthreads();

    // append kept entries to the per-image list (order-free: key is total order)
    for (int k2 = tid; k2 < N; k2 += 64) {
        if (keep[k2]) {
            int pos = atomicAdd(&g_cnt[b], 1);
            if (pos < CAP) {
                unsigned fi = (unsigned)(ci * KK + k2);
                img_keys[(size_t)b * CAP + pos] =
                    (keys[k2] & 0xFFFFFFFF00000000ULL) | (unsigned)(~fi);
                img_boxes[(size_t)b * CAP + pos] =
                    make_float4(bx1[k2], by1[k2], bx2[k2], by2[k2]);
            }
        }
    }
}

// ---- Kernel C: per-image exact top-100 via ballot binary-search ----
__global__ __launch_bounds__(256) void topd_kernel(
        const ull*    __restrict__ img_keys,
        const float4* __restrict__ img_boxes,
        const int*    __restrict__ g_cnt,
        float*        __restrict__ out) {
    __shared__ unsigned sb[CAP];      // 64 KB staged score bits
    __shared__ unsigned wred[8];      // double-buffered cross-wave partials
    __shared__ ull      pk[256];
    __shared__ int      ps[256];
    __shared__ int      sh_cnt;

    const int b   = blockIdx.x;
    const int tid = threadIdx.x;
    int M = g_cnt[b]; if (M > CAP) M = CAP;
    const ull* kp = img_keys + (size_t)b * CAP;

    for (int i = tid; i < M; i += 256) sb[i] = (unsigned)(kp[i] >> 32);
    __syncthreads();

    // largest T with count(sb >= T) >= DD.  scores in (0.05, 1.0] strictly.
    unsigned lo = 0x3D4CCCCDu;        // 0.05f: count(>=lo) = M >= DD
    unsigned hi = 0x40000000u;        // 2.0f:  count(>=hi) = 0
    int par = 0;
    while (hi - lo > 1u) {
        unsigned mid = lo + ((hi - lo) >> 1);
        int c = 0;
        for (int i = tid; i < M; i += 256) c += (sb[i] >= mid) ? 1 : 0;
        for (int off = 32; off; off >>= 1) c += __shfl_down(c, off);
        if ((tid & 63) == 0) wred[par * 4 + (tid >> 6)] = (unsigned)c;
        __syncthreads();
        int total = (int)(wred[par * 4] + wred[par * 4 + 1] +
                          wred[par * 4 + 2] + wred[par * 4 + 3]);
        if (total >= DD) lo = mid; else hi = mid;
        par ^= 1;
    }
    const unsigned T = lo;

    if (tid == 0) sh_cnt = 0;
    __syncthreads();
    for (int i = tid; i < M; i += 256) {
        if (sb[i] >= T) {
            int p = atomicAdd(&sh_cnt, 1);
            if (p < 256) { pk[p] = kp[i]; ps[p] = i; }
        }
    }
    __syncthreads();
    int ngath = sh_cnt; if (ngath > 256) ngath = 256;   // expected ~100-101
    const int sortN = (ngath <= 128) ? 128 : 256;
    for (int i = tid; i < sortN; i += 256) if (i >= ngath) { pk[i] = 0ULL; ps[i] = -1; }
    __syncthreads();

    // bitonic sort pairs desc by key (score, then lower flat idx)
    for (int k = 2; k <= sortN; k <<= 1) {
        for (int j = k >> 1; j > 0; j >>= 1) {
            for (int i = tid; i < sortN; i += 256) {
                int ixj = i ^ j;
                if (ixj > i) {
                    bool desc = ((i & k) == 0);
                    ull a = pk[i], c = pk[ixj];
                    if (desc ? (a < c) : (a > c)) {
                        pk[i] = c; pk[ixj] = a;
                        int t = ps[i]; ps[i] = ps[ixj]; ps[ixj] = t;
                    }
                }
            }
            __syncthreads();
        }
    }

    if (tid < DD) {
        float s; float4 bb; int label;
        if (tid < ngath) {
            ull key = pk[tid];
            unsigned fi = ~(unsigned)(key & 0xFFFFFFFFu);
            s  = __uint_as_float((unsigned)(key >> 32));
            bb = img_boxes[(size_t)b * CAP + ps[tid]];
            label = (int)(fi / KK) + 1;
        } else {
            s = -1.0f; bb = make_float4(0.0f, 0.0f, 0.0f, 0.0f); label = 0;
        }
        out[(size_t)(b * DD + tid) * 4 + 0] = bb.x;
        out[(size_t)(b * DD + tid) * 4 + 1] = bb.y;
        out[(size_t)(b * DD + tid) * 4 + 2] = bb.z;
        out[(size_t)(b * DD + tid) * 4 + 3] = bb.w;
        out[(size_t)BB * DD * 4 + b * DD + tid] = s;
        out[(size_t)BB * DD * 4 + BB * DD + b * DD + tid] = (float)label;
    }
}

extern "C" void kernel_launch(void* const* d_in, const int* in_sizes, int n_in,
                              void* d_out, int out_size, void* d_ws, size_t ws_size,
                              hipStream_t stream) {
    const float* logits    = (const float*)d_in[0];   // [B*R, 81]
    const float* box_reg   = (const float*)d_in[1];   // [B*R, 324]
    const float* proposals = (const float*)d_in[2];   // [B*R, 4]
    float* out = (float*)d_out;

    char* ws = (char*)d_ws;
    int*    cls_cnt   = (int*)ws;                       //     5,120 B
    int*    g_cnt     = (int*)(ws + 5120);              //        64 B
    ull*    cand2     = (ull*)(ws + 5184);              // 5,242,880 B
    ull*    img_keys  = (ull*)(ws + 5248064);           // 2,097,152 B
    float4* img_boxes = (float4*)(ws + 7345216);        // 4,194,304 B

    hipMemsetAsync(ws, 0, 5184, stream);                // zero both counter arrays
    softmax_cand_kernel<<<(BB * RR) / 64, 256, 0, stream>>>(logits, cand2, cls_cnt);
    percls_kernel<<<BB * NC, 64, 0, stream>>>(cand2, cls_cnt, box_reg, proposals,
                                              img_keys, img_boxes, g_cnt);
    topd_kernel<<<BB, 256, 0, stream>>>(img_keys, img_boxes, g_cnt, out);
}

// Round 4
// 269.631 us; speedup vs baseline: 1.5498x; 1.3968x over previous
//
#include <hip/hip_runtime.h>
#include <math.h>

#define BB   16
#define RR   4096
#define NC   80          // foreground classes
#define KK   300
#define DD   100
#define CCAP 512         // per-(image,class) candidate cap (expected ~118, sigma ~11)
#define CAP  16384       // per-image kept-candidate cap (expected ~8800)
#define LCAP 48          // per-(block,class) local cap (expected ~7.4, sigma ~2.7)

typedef unsigned long long ull;

// ---- Kernel A: register-resident softmax + block-aggregated candidate emit ----
// One row per thread. Serial c=0..80 max/exp/sum order kept bit-identical to
// the reference path that has passed with absmax 0.0.
__global__ __launch_bounds__(256) void softmax_cand_kernel(
        const float* __restrict__ logits,
        ull*         __restrict__ cand2,     // [BB*NC][CCAP]
        int*         __restrict__ cls_cnt) { // [BB*NC]
    __shared__ ull lbuf[NC * LCAP];          // 30720 B
    __shared__ int lhist[NC];
    __shared__ int gbase[NC];

    const int tid = threadIdx.x;
    const int row = blockIdx.x * 256 + tid;  // 65536 rows total, 256 blocks
    const int b   = blockIdx.x >> 4;         // 16 blocks per image

    for (int i = tid; i < NC; i += 256) lhist[i] = 0;
    __syncthreads();

    float v[81];
    const float* rp = logits + (size_t)row * 81;
    #pragma unroll
    for (int c = 0; c < 81; ++c) v[c] = rp[c];

    float m = -1e30f;
    #pragma unroll
    for (int c = 0; c < 81; ++c) m = fmaxf(m, v[c]);

    float s = 0.0f;
    #pragma unroll
    for (int c = 0; c < 81; ++c) { float e = expf(v[c] - m); v[c] = e; s += e; }

    #pragma unroll
    for (int c = 1; c < 81; ++c) {
        float p = v[c] / s;
        if (p > 0.05f) {
            int ci  = c - 1;
            int pos = atomicAdd(&lhist[ci], 1);        // LDS atomic (cheap)
            if (pos < LCAP)
                lbuf[ci * LCAP + pos] =
                    ((ull)__float_as_uint(p) << 32) | (unsigned)(~(unsigned)(row & 4095));
        }
    }
    __syncthreads();

    if (tid < NC) {
        int h = lhist[tid]; if (h > LCAP) h = LCAP;
        gbase[tid] = atomicAdd(&cls_cnt[b * NC + tid], h);  // 80 global atomics/block
    }
    __syncthreads();

    for (int idx = tid; idx < NC * LCAP; idx += 256) {
        int ci = idx / LCAP, j = idx - ci * LCAP;
        int h  = lhist[ci]; if (h > LCAP) h = LCAP;
        if (j < h) {
            int pos = gbase[ci] + j;
            if (pos < CCAP)
                cand2[(size_t)(b * NC + ci) * CCAP + pos] = lbuf[idx];
        }
    }
}

// ---- Kernel B: ONE WAVE per (image,class): sort + decode + NMS + append ----
__global__ __launch_bounds__(64) void percls_kernel(
        const ull*   __restrict__ cand2,
        const int*   __restrict__ cls_cnt,
        const float* __restrict__ box_reg,
        const float* __restrict__ proposals,
        ull*         __restrict__ img_keys,   // [BB][CAP]
        float4*      __restrict__ img_boxes,  // [BB][CAP]
        int*         __restrict__ g_cnt) {    // [BB]
    #pragma clang fp contract(off)
    __shared__ ull   keys[CCAP];
    __shared__ float bx1[KK], by1[KK], bx2[KK], by2[KK], bar[KK];
    __shared__ int   keep[KK];

    const int bid = blockIdx.x;   // 0..1279
    const int b   = bid / NC;
    const int ci  = bid % NC;
    const int tid = threadIdx.x;  // 0..63 (single wave)

    int M = cls_cnt[bid]; if (M > CCAP) M = CCAP;
    int sortN = 2; while (sortN < M) sortN <<= 1;

    for (int i = tid; i < sortN; i += 64)
        keys[i] = (i < M) ? cand2[(size_t)bid * CCAP + i] : 0ULL;
    __syncthreads();

    for (int k = 2; k <= sortN; k <<= 1) {
        for (int j = k >> 1; j > 0; j >>= 1) {
            for (int i = tid; i < sortN; i += 64) {
                int ixj = i ^ j;
                if (ixj > i) {
                    bool desc = ((i & k) == 0);
                    ull a = keys[i], c = keys[ixj];
                    if (desc ? (a < c) : (a > c)) { keys[i] = c; keys[ixj] = a; }
                }
            }
            __syncthreads();
        }
    }

    const int N = (M < KK) ? M : KK;

    for (int k2 = tid; k2 < N; k2 += 64) {
        unsigned r = ~(unsigned)(keys[k2] & 0xFFFFFFFFu);
        size_t n = (size_t)b * RR + r;
        const float4 pr = *(const float4*)(proposals + n * 4);
        const float4 rg = *(const float4*)(box_reg + n * 324 + (size_t)(ci + 1) * 4);
        float dx = rg.x / 10.0f;
        float dy = rg.y / 10.0f;
        float dw = fminf(rg.z / 5.0f, 4.135166556742356f);
        float dh = fminf(rg.w / 5.0f, 4.135166556742356f);
        float w  = pr.z - pr.x + 1.0f;
        float h  = pr.w - pr.y + 1.0f;
        float cx = pr.x + 0.5f * w;
        float cy = pr.y + 0.5f * h;
        float pcx = dx * w + cx;
        float pcy = dy * h + cy;
        float pw  = expf(dw) * w;
        float ph  = expf(dh) * h;
        float x1 = pcx - 0.5f * pw;
        float y1 = pcy - 0.5f * ph;
        float x2 = pcx + 0.5f * pw - 1.0f;
        float y2 = pcy + 0.5f * ph - 1.0f;
        x1 = fminf(fmaxf(x1, 0.0f), 1332.0f);
        y1 = fminf(fmaxf(y1, 0.0f), 799.0f);
        x2 = fminf(fmaxf(x2, 0.0f), 1332.0f);
        y2 = fminf(fmaxf(y2, 0.0f), 799.0f);
        bx1[k2] = x1; by1[k2] = y1; bx2[k2] = x2; by2[k2] = y2;
        bar[k2] = (x2 - x1 + 1.0f) * (y2 - y1 + 1.0f);
        keep[k2] = 1;
    }
    __syncthreads();

    for (int i = 0; i < N; ++i) {
        __syncthreads();
        if (!keep[i]) continue;
        float ax1 = bx1[i], ay1 = by1[i], ax2 = bx2[i], ay2 = by2[i], aar = bar[i];
        for (int j = i + 1 + tid; j < N; j += 64) {
            if (!keep[j]) continue;
            float ltx = fmaxf(ax1, bx1[j]);
            float lty = fmaxf(ay1, by1[j]);
            float rbx = fminf(ax2, bx2[j]);
            float rby = fminf(ay2, by2[j]);
            float iw  = fmaxf(rbx - ltx + 1.0f, 0.0f);
            float ih  = fmaxf(rby - lty + 1.0f, 0.0f);
            float inter = iw * ih;
            float iou   = inter / ((aar + bar[j]) - inter);
            if (iou > 0.5f) keep[j] = 0;
        }
    }
    __syncthreads();

    for (int k2 = tid; k2 < N; k2 += 64) {
        if (keep[k2]) {
            int pos = atomicAdd(&g_cnt[b], 1);
            if (pos < CAP) {
                unsigned fi = (unsigned)(ci * KK + k2);
                img_keys[(size_t)b * CAP + pos] =
                    (keys[k2] & 0xFFFFFFFF00000000ULL) | (unsigned)(~fi);
                img_boxes[(size_t)b * CAP + pos] =
                    make_float4(bx1[k2], by1[k2], bx2[k2], by2[k2]);
            }
        }
    }
}

// ---- Kernel C: per-image exact top-100 via ballot binary-search ----
__global__ __launch_bounds__(256) void topd_kernel(
        const ull*    __restrict__ img_keys,
        const float4* __restrict__ img_boxes,
        const int*    __restrict__ g_cnt,
        float*        __restrict__ out) {
    __shared__ unsigned sb[CAP];
    __shared__ unsigned wred[8];
    __shared__ ull      pk[256];
    __shared__ int      ps[256];
    __shared__ int      sh_cnt;

    const int b   = blockIdx.x;
    const int tid = threadIdx.x;
    int M = g_cnt[b]; if (M > CAP) M = CAP;
    const ull* kp = img_keys + (size_t)b * CAP;

    for (int i = tid; i < M; i += 256) sb[i] = (unsigned)(kp[i] >> 32);
    __syncthreads();

    unsigned lo = 0x3D4CCCCDu;        // 0.05f
    unsigned hi = 0x40000000u;        // 2.0f
    int par = 0;
    while (hi - lo > 1u) {
        unsigned mid = lo + ((hi - lo) >> 1);
        int c = 0;
        for (int i = tid; i < M; i += 256) c += (sb[i] >= mid) ? 1 : 0;
        for (int off = 32; off; off >>= 1) c += __shfl_down(c, off);
        if ((tid & 63) == 0) wred[par * 4 + (tid >> 6)] = (unsigned)c;
        __syncthreads();
        int total = (int)(wred[par * 4] + wred[par * 4 + 1] +
                          wred[par * 4 + 2] + wred[par * 4 + 3]);
        if (total >= DD) lo = mid; else hi = mid;
        par ^= 1;
    }
    const unsigned T = lo;

    if (tid == 0) sh_cnt = 0;
    __syncthreads();
    for (int i = tid; i < M; i += 256) {
        if (sb[i] >= T) {
            int p = atomicAdd(&sh_cnt, 1);
            if (p < 256) { pk[p] = kp[i]; ps[p] = i; }
        }
    }
    __syncthreads();
    int ngath = sh_cnt; if (ngath > 256) ngath = 256;
    const int sortN = (ngath <= 128) ? 128 : 256;
    for (int i = tid; i < sortN; i += 256) if (i >= ngath) { pk[i] = 0ULL; ps[i] = -1; }
    __syncthreads();

    for (int k = 2; k <= sortN; k <<= 1) {
        for (int j = k >> 1; j > 0; j >>= 1) {
            for (int i = tid; i < sortN; i += 256) {
                int ixj = i ^ j;
                if (ixj > i) {
                    bool desc = ((i & k) == 0);
                    ull a = pk[i], c = pk[ixj];
                    if (desc ? (a < c) : (a > c)) {
                        pk[i] = c; pk[ixj] = a;
                        int t = ps[i]; ps[i] = ps[ixj]; ps[ixj] = t;
                    }
                }
            }
            __syncthreads();
        }
    }

    if (tid < DD) {
        float s; float4 bb; int label;
        if (tid < ngath) {
            ull key = pk[tid];
            unsigned fi = ~(unsigned)(key & 0xFFFFFFFFu);
            s  = __uint_as_float((unsigned)(key >> 32));
            bb = img_boxes[(size_t)b * CAP + ps[tid]];
            label = (int)(fi / KK) + 1;
        } else {
            s = -1.0f; bb = make_float4(0.0f, 0.0f, 0.0f, 0.0f); label = 0;
        }
        out[(size_t)(b * DD + tid) * 4 + 0] = bb.x;
        out[(size_t)(b * DD + tid) * 4 + 1] = bb.y;
        out[(size_t)(b * DD + tid) * 4 + 2] = bb.z;
        out[(size_t)(b * DD + tid) * 4 + 3] = bb.w;
        out[(size_t)BB * DD * 4 + b * DD + tid] = s;
        out[(size_t)BB * DD * 4 + BB * DD + b * DD + tid] = (float)label;
    }
}

extern "C" void kernel_launch(void* const* d_in, const int* in_sizes, int n_in,
                              void* d_out, int out_size, void* d_ws, size_t ws_size,
                              hipStream_t stream) {
    const float* logits    = (const float*)d_in[0];   // [B*R, 81]
    const float* box_reg   = (const float*)d_in[1];   // [B*R, 324]
    const float* proposals = (const float*)d_in[2];   // [B*R, 4]
    float* out = (float*)d_out;

    char* ws = (char*)d_ws;
    int*    cls_cnt   = (int*)ws;                       //     5,120 B
    int*    g_cnt     = (int*)(ws + 5120);              //        64 B
    ull*    cand2     = (ull*)(ws + 5184);              // 5,242,880 B
    ull*    img_keys  = (ull*)(ws + 5248064);           // 2,097,152 B
    float4* img_boxes = (float4*)(ws + 7345216);        // 4,194,304 B

    hipMemsetAsync(ws, 0, 5184, stream);
    softmax_cand_kernel<<<(BB * RR) / 256, 256, 0, stream>>>(logits, cand2, cls_cnt);
    percls_kernel<<<BB * NC, 64, 0, stream>>>(cand2, cls_cnt, box_reg, proposals,
                                              img_keys, img_boxes, g_cnt);
    topd_kernel<<<BB, 256, 0, stream>>>(img_keys, img_boxes, g_cnt, out);
}

// Round 5
// 262.043 us; speedup vs baseline: 1.5947x; 1.0290x over previous
//
#include <hip/hip_runtime.h>
#include <math.h>

#define BB   16
#define RR   4096
#define NC   80          // foreground classes
#define KK   300
#define DD   100
#define CCAP 512         // per-(image,class) candidate cap (expected ~118, sigma ~11)
#define CAP  16384       // per-image kept-candidate cap
#define LCAP 48          // per-(block,class) local cap in kernel A
#define NW   5           // 5*64 = 320 >= KK bitmask words

typedef unsigned long long ull;

// ---- Kernel A: register-resident softmax + block-aggregated candidate emit ----
__global__ __launch_bounds__(256) void softmax_cand_kernel(
        const float* __restrict__ logits,
        ull*         __restrict__ cand2,     // [BB*NC][CCAP]
        int*         __restrict__ cls_cnt) { // [BB*NC]
    __shared__ ull lbuf[NC * LCAP];
    __shared__ int lhist[NC];
    __shared__ int gbase[NC];

    const int tid = threadIdx.x;
    const int row = blockIdx.x * 256 + tid;
    const int b   = blockIdx.x >> 4;

    for (int i = tid; i < NC; i += 256) lhist[i] = 0;
    __syncthreads();

    float v[81];
    const float* rp = logits + (size_t)row * 81;
    #pragma unroll
    for (int c = 0; c < 81; ++c) v[c] = rp[c];

    float m = -1e30f;
    #pragma unroll
    for (int c = 0; c < 81; ++c) m = fmaxf(m, v[c]);

    float s = 0.0f;
    #pragma unroll
    for (int c = 0; c < 81; ++c) { float e = expf(v[c] - m); v[c] = e; s += e; }

    #pragma unroll
    for (int c = 1; c < 81; ++c) {
        float p = v[c] / s;
        if (p > 0.05f) {
            int ci  = c - 1;
            int pos = atomicAdd(&lhist[ci], 1);
            if (pos < LCAP)
                lbuf[ci * LCAP + pos] =
                    ((ull)__float_as_uint(p) << 32) | (unsigned)(~(unsigned)(row & 4095));
        }
    }
    __syncthreads();

    if (tid < NC) {
        int h = lhist[tid]; if (h > LCAP) h = LCAP;
        gbase[tid] = atomicAdd(&cls_cnt[b * NC + tid], h);
    }
    __syncthreads();

    for (int idx = tid; idx < NC * LCAP; idx += 256) {
        int ci = idx / LCAP, j = idx - ci * LCAP;
        int h  = lhist[ci]; if (h > LCAP) h = LCAP;
        if (j < h) {
            int pos = gbase[ci] + j;
            if (pos < CCAP)
                cand2[(size_t)(b * NC + ci) * CCAP + pos] = lbuf[idx];
        }
    }
}

// ---- Kernel B: ONE WAVE per (image,class): sort + decode + BITMASK NMS ----
__global__ __launch_bounds__(64) void percls_kernel(
        const ull*   __restrict__ cand2,
        const int*   __restrict__ cls_cnt,
        const float* __restrict__ box_reg,
        const float* __restrict__ proposals,
        ull*         __restrict__ img_keys,   // [BB][CAP]
        float4*      __restrict__ img_boxes,  // [BB][CAP]
        int*         __restrict__ g_cnt) {    // [BB]
    #pragma clang fp contract(off)
    __shared__ ull   keys[CCAP];
    __shared__ float bx1[KK], by1[KK], bx2[KK], by2[KK], bar[KK];

    const int bid = blockIdx.x;
    const int b   = bid / NC;
    const int ci  = bid % NC;
    const int tid = threadIdx.x;   // 0..63, single wave

    int M = cls_cnt[bid]; if (M > CCAP) M = CCAP;
    int sortN = 2; while (sortN < M) sortN <<= 1;

    for (int i = tid; i < sortN; i += 64)
        keys[i] = (i < M) ? cand2[(size_t)bid * CCAP + i] : 0ULL;
    __syncthreads();

    for (int k = 2; k <= sortN; k <<= 1) {
        for (int j = k >> 1; j > 0; j >>= 1) {
            for (int i = tid; i < sortN; i += 64) {
                int ixj = i ^ j;
                if (ixj > i) {
                    bool desc = ((i & k) == 0);
                    ull a = keys[i], c = keys[ixj];
                    if (desc ? (a < c) : (a > c)) { keys[i] = c; keys[ixj] = a; }
                }
            }
            __syncthreads();
        }
    }

    const int N = (M < KK) ? M : KK;

    // decode + clip (reference op order; contract off)
    for (int k2 = tid; k2 < N; k2 += 64) {
        unsigned r = ~(unsigned)(keys[k2] & 0xFFFFFFFFu);
        size_t n = (size_t)b * RR + r;
        const float4 pr = *(const float4*)(proposals + n * 4);
        const float4 rg = *(const float4*)(box_reg + n * 324 + (size_t)(ci + 1) * 4);
        float dx = rg.x / 10.0f;
        float dy = rg.y / 10.0f;
        float dw = fminf(rg.z / 5.0f, 4.135166556742356f);
        float dh = fminf(rg.w / 5.0f, 4.135166556742356f);
        float w  = pr.z - pr.x + 1.0f;
        float h  = pr.w - pr.y + 1.0f;
        float cx = pr.x + 0.5f * w;
        float cy = pr.y + 0.5f * h;
        float pcx = dx * w + cx;
        float pcy = dy * h + cy;
        float pw  = expf(dw) * w;
        float ph  = expf(dh) * h;
        float x1 = pcx - 0.5f * pw;
        float y1 = pcy - 0.5f * ph;
        float x2 = pcx + 0.5f * pw - 1.0f;
        float y2 = pcy + 0.5f * ph - 1.0f;
        x1 = fminf(fmaxf(x1, 0.0f), 1332.0f);
        y1 = fminf(fmaxf(y1, 0.0f), 799.0f);
        x2 = fminf(fmaxf(x2, 0.0f), 1332.0f);
        y2 = fminf(fmaxf(y2, 0.0f), 799.0f);
        bx1[k2] = x1; by1[k2] = y1; bx2[k2] = x2; by2[k2] = y2;
        bar[k2] = (x2 - x1 + 1.0f) * (y2 - y1 + 1.0f);
    }
    __syncthreads();

    // keep mask (wave-uniform value, one bit per candidate)
    ull keepw[NW];
    #pragma unroll
    for (int w = 0; w < NW; ++w) {
        int lo = w * 64;
        keepw[w] = (N >= lo + 64) ? ~0ULL : (N <= lo ? 0ULL : ((1ULL << (N - lo)) - 1ULL));
    }

    // tile-by-tile: compute suppression rows in registers, resolve via readlane
    #pragma unroll
    for (int t = 0; t < NW; ++t) {
        if (t * 64 >= N) break;
        const int i = t * 64 + tid;          // this lane's row
        float ax1 = 0, ay1 = 0, ax2 = 0, ay2 = 0, aar = 0;
        if (i < N) { ax1 = bx1[i]; ay1 = by1[i]; ax2 = bx2[i]; ay2 = by2[i]; aar = bar[i]; }
        ull sup[NW];
        #pragma unroll
        for (int w = 0; w < NW; ++w) {
            ull mword = 0ULL;
            if (w >= t && w * 64 < N) {
                int jlo = w * 64; if (jlo < i + 1) jlo = i + 1;
                int jhi = w * 64 + 64; if (jhi > N) jhi = N;
                for (int j = jlo; j < jhi; ++j) {
                    float ltx = fmaxf(ax1, bx1[j]);
                    float lty = fmaxf(ay1, by1[j]);
                    float rbx = fminf(ax2, bx2[j]);
                    float rby = fminf(ay2, by2[j]);
                    float iw  = fmaxf(rbx - ltx + 1.0f, 0.0f);
                    float ih  = fmaxf(rby - lty + 1.0f, 0.0f);
                    float inter = iw * ih;
                    float iou   = inter / ((aar + bar[j]) - inter);
                    if (iou > 0.5f) mword |= 1ULL << (j - w * 64);
                }
            }
            sup[w] = mword;
        }
        // greedy resolve of this tile (uniform; shfl -> readlane broadcasts)
        const int lmax = (N - t * 64 < 64) ? (N - t * 64) : 64;
        for (int l = 0; l < lmax; ++l) {
            if ((keepw[t] >> l) & 1ULL) {
                #pragma unroll
                for (int w = 0; w < NW; ++w) {
                    if (w >= t && w * 64 < N)
                        keepw[w] &= ~__shfl(sup[w], l);
                }
            }
        }
    }

    // append kept entries (key is a total order -> order-free)
    #pragma unroll
    for (int t = 0; t < NW; ++t) {
        int k2 = t * 64 + tid;
        if (t * 64 >= N) break;
        if (k2 < N && ((keepw[t] >> tid) & 1ULL)) {
            int pos = atomicAdd(&g_cnt[b], 1);
            if (pos < CAP) {
                unsigned fi = (unsigned)(ci * KK + k2);
                img_keys[(size_t)b * CAP + pos] =
                    (keys[k2] & 0xFFFFFFFF00000000ULL) | (unsigned)(~fi);
                img_boxes[(size_t)b * CAP + pos] =
                    make_float4(bx1[k2], by1[k2], bx2[k2], by2[k2]);
            }
        }
    }
}

// ---- Kernel C: per-image exact top-100 via ballot binary-search ----
__global__ __launch_bounds__(256) void topd_kernel(
        const ull*    __restrict__ img_keys,
        const float4* __restrict__ img_boxes,
        const int*    __restrict__ g_cnt,
        float*        __restrict__ out) {
    __shared__ unsigned sb[CAP];
    __shared__ unsigned wred[8];
    __shared__ ull      pk[256];
    __shared__ int      ps[256];
    __shared__ int      sh_cnt;

    const int b   = blockIdx.x;
    const int tid = threadIdx.x;
    int M = g_cnt[b]; if (M > CAP) M = CAP;
    const ull* kp = img_keys + (size_t)b * CAP;

    for (int i = tid; i < M; i += 256) sb[i] = (unsigned)(kp[i] >> 32);
    __syncthreads();

    unsigned lo = 0x3D4CCCCDu;        // 0.05f
    unsigned hi = 0x40000000u;        // 2.0f
    int par = 0;
    while (hi - lo > 1u) {
        unsigned mid = lo + ((hi - lo) >> 1);
        int c = 0;
        for (int i = tid; i < M; i += 256) c += (sb[i] >= mid) ? 1 : 0;
        for (int off = 32; off; off >>= 1) c += __shfl_down(c, off);
        if ((tid & 63) == 0) wred[par * 4 + (tid >> 6)] = (unsigned)c;
        __syncthreads();
        int total = (int)(wred[par * 4] + wred[par * 4 + 1] +
                          wred[par * 4 + 2] + wred[par * 4 + 3]);
        if (total >= DD) lo = mid; else hi = mid;
        par ^= 1;
    }
    const unsigned T = lo;

    if (tid == 0) sh_cnt = 0;
    __syncthreads();
    for (int i = tid; i < M; i += 256) {
        if (sb[i] >= T) {
            int p = atomicAdd(&sh_cnt, 1);
            if (p < 256) { pk[p] = kp[i]; ps[p] = i; }
        }
    }
    __syncthreads();
    int ngath = sh_cnt; if (ngath > 256) ngath = 256;
    const int sortN = (ngath <= 128) ? 128 : 256;
    for (int i = tid; i < sortN; i += 256) if (i >= ngath) { pk[i] = 0ULL; ps[i] = -1; }
    __syncthreads();

    for (int k = 2; k <= sortN; k <<= 1) {
        for (int j = k >> 1; j > 0; j >>= 1) {
            for (int i = tid; i < sortN; i += 256) {
                int ixj = i ^ j;
                if (ixj > i) {
                    bool desc = ((i & k) == 0);
                    ull a = pk[i], c = pk[ixj];
                    if (desc ? (a < c) : (a > c)) {
                        pk[i] = c; pk[ixj] = a;
                        int t = ps[i]; ps[i] = ps[ixj]; ps[ixj] = t;
                    }
                }
            }
            __syncthreads();
        }
    }

    if (tid < DD) {
        float s; float4 bb; int label;
        if (tid < ngath) {
            ull key = pk[tid];
            unsigned fi = ~(unsigned)(key & 0xFFFFFFFFu);
            s  = __uint_as_float((unsigned)(key >> 32));
            bb = img_boxes[(size_t)b * CAP + ps[tid]];
            label = (int)(fi / KK) + 1;
        } else {
            s = -1.0f; bb = make_float4(0.0f, 0.0f, 0.0f, 0.0f); label = 0;
        }
        out[(size_t)(b * DD + tid) * 4 + 0] = bb.x;
        out[(size_t)(b * DD + tid) * 4 + 1] = bb.y;
        out[(size_t)(b * DD + tid) * 4 + 2] = bb.z;
        out[(size_t)(b * DD + tid) * 4 + 3] = bb.w;
        out[(size_t)BB * DD * 4 + b * DD + tid] = s;
        out[(size_t)BB * DD * 4 + BB * DD + b * DD + tid] = (float)label;
    }
}

extern "C" void kernel_launch(void* const* d_in, const int* in_sizes, int n_in,
                              void* d_out, int out_size, void* d_ws, size_t ws_size,
                              hipStream_t stream) {
    const float* logits    = (const float*)d_in[0];
    const float* box_reg   = (const float*)d_in[1];
    const float* proposals = (const float*)d_in[2];
    float* out = (float*)d_out;

    char* ws = (char*)d_ws;
    int*    cls_cnt   = (int*)ws;
    int*    g_cnt     = (int*)(ws + 5120);
    ull*    cand2     = (ull*)(ws + 5184);
    ull*    img_keys  = (ull*)(ws + 5248064);
    float4* img_boxes = (float4*)(ws + 7345216);

    hipMemsetAsync(ws, 0, 5184, stream);
    softmax_cand_kernel<<<(BB * RR) / 256, 256, 0, stream>>>(logits, cand2, cls_cnt);
    percls_kernel<<<BB * NC, 64, 0, stream>>>(cand2, cls_cnt, box_reg, proposals,
                                              img_keys, img_boxes, g_cnt);
    topd_kernel<<<BB, 256, 0, stream>>>(img_keys, img_boxes, g_cnt, out);
}